// Round 3
// baseline (483.867 us; speedup 1.0000x reference)
//
#include <hip/hip_runtime.h>

#define VOCAB 100000
#define EMBED 128
#define MAX_PATH 20
#define BATCH 32768
#define WPB 4                    // waves per block (block = 256 threads)
#define NBLOCKS (BATCH / WPB)    // 8192

// One 64-lane wave per batch element; wave split into 4 groups of 16 lanes,
// each group handling one path node per unrolled step (4 nodes/wave-inst).
// All 5 steps' gathers are issued before any math (no break, no control flow)
// so the ~300-900cyc IF$/HBM gather latency is exposed once, not 5x.
// Padded nodes have path id 0 (reference zeroes them) -> row 0 stays L1-hot;
// mask == |code| so the masks input is unused.
// Final mean fused via last-block-reduce (device-scope atomic counter).
__global__ __launch_bounds__(256) void hs_loss_kernel(
    const int* __restrict__ center, const int* __restrict__ target,
    const float* __restrict__ in_emb, const float* __restrict__ inner_vec,
    const int* __restrict__ paths, const float* __restrict__ codes,
    float* __restrict__ partials, unsigned int* __restrict__ counter,
    float* __restrict__ out)
{
    const int wave = threadIdx.x >> 6;
    const int lane = threadIdx.x & 63;
    const int g    = lane >> 4;   // group 0..3
    const int gl   = lane & 15;   // lane within group
    const int b = blockIdx.x * WPB + wave;

    const int c = center[b];
    const int t = target[b];

    const float4* hp = (const float4*)(in_emb + (size_t)c * EMBED);
    const float4 h0 = hp[2 * gl];
    const float4 h1 = hp[2 * gl + 1];

    // Group g's 5 (path, code) pairs: nodes g, g+4, ..., g+16.
    // Within a group all 16 lanes load the same address -> broadcast.
    const int base = t * MAX_PATH + g;
    int   p[5];
    float cd[5];
    #pragma unroll
    for (int j = 0; j < 5; ++j) {
        p[j]  = paths[base + 4 * j];
        cd[j] = codes[base + 4 * j];
    }

    // Phase 1: issue all gathers (10 x dwordx4 in flight per lane).
    float4 a0[5], a1[5];
    #pragma unroll
    for (int j = 0; j < 5; ++j) {
        const float4* ivp = (const float4*)(inner_vec + (size_t)p[j] * EMBED);
        a0[j] = ivp[2 * gl];
        a1[j] = ivp[2 * gl + 1];
    }

    // Phase 2: math.
    float acc = 0.f;
    #pragma unroll
    for (int j = 0; j < 5; ++j) {
        float d = h0.x * a0[j].x;
        d = fmaf(h0.y, a0[j].y, d);
        d = fmaf(h0.z, a0[j].z, d);
        d = fmaf(h0.w, a0[j].w, d);
        d = fmaf(h1.x, a1[j].x, d);
        d = fmaf(h1.y, a1[j].y, d);
        d = fmaf(h1.z, a1[j].z, d);
        d = fmaf(h1.w, a1[j].w, d);
        d += __shfl_xor(d, 1, 64);
        d += __shfl_xor(d, 2, 64);
        d += __shfl_xor(d, 4, 64);
        d += __shfl_xor(d, 8, 64);
        const float x  = cd[j] * d;
        const float ls = fminf(x, 0.f) - __logf(1.f + __expf(-fabsf(x)));
        acc = fmaf(fabsf(cd[j]), ls, acc);   // |code| == mask (0 on padding)
    }
    acc += __shfl_xor(acc, 16, 64);
    acc += __shfl_xor(acc, 32, 64);          // sum over the 4 groups

    __shared__ float ws[WPB];
    __shared__ bool  last;
    if (lane == 0) ws[wave] = -acc;
    __syncthreads();
    if (threadIdx.x == 0) {
        partials[blockIdx.x] = ws[0] + ws[1] + ws[2] + ws[3];
        __threadfence();                      // publish partial (device scope)
        unsigned int old = atomicAdd(counter, 1u);
        last = (old == NBLOCKS - 1);
    }
    __syncthreads();
    if (last) {
        __threadfence();                      // acquire all partials
        float s = 0.f;
        for (int i = threadIdx.x; i < NBLOCKS; i += 256) s += partials[i];
        #pragma unroll
        for (int off = 32; off; off >>= 1) s += __shfl_xor(s, off, 64);
        __shared__ float fin[WPB];
        if ((threadIdx.x & 63) == 0) fin[threadIdx.x >> 6] = s;
        __syncthreads();
        if (threadIdx.x == 0)
            out[0] = (fin[0] + fin[1] + fin[2] + fin[3]) / (float)BATCH;
    }
}

extern "C" void kernel_launch(void* const* d_in, const int* in_sizes, int n_in,
                              void* d_out, int out_size, void* d_ws, size_t ws_size,
                              hipStream_t stream) {
    const int*   center    = (const int*)d_in[0];
    const int*   target    = (const int*)d_in[1];
    const float* in_emb    = (const float*)d_in[2];
    const float* inner_vec = (const float*)d_in[3];
    const int*   paths     = (const int*)d_in[4];
    const float* codes     = (const float*)d_in[5];
    // d_in[6] (masks) intentionally unused: mask == |code|
    float* out = (float*)d_out;

    // d_ws layout: [0..255] counter (+pad), [256 ...] 8192 float partials
    unsigned int* counter  = (unsigned int*)d_ws;
    float*        partials = (float*)((char*)d_ws + 256);

    // d_ws is re-poisoned to 0xAA before every launch -> zero the counter
    // each call (memset node is graph-capture legal).
    hipMemsetAsync(d_ws, 0, 256, stream);
    hs_loss_kernel<<<NBLOCKS, 256, 0, stream>>>(
        center, target, in_emb, inner_vec, paths, codes,
        partials, counter, out);
}

// Round 4
// 177.877 us; speedup vs baseline: 2.7202x; 2.7202x over previous
//
#include <hip/hip_runtime.h>

#define VOCAB 100000
#define EMBED 128
#define MAX_PATH 20
#define BATCH 32768
#define WPB 4                    // waves per block (block = 256 threads)
#define NBLOCKS (BATCH / WPB)    // 8192

// One 64-lane wave per batch element; wave split into 8 groups of 8 lanes.
// Each group handles one path node per batch-step -> 8 nodes in flight,
// only 3 serial steps (vs 5 with 16-lane groups). Explicit 1-deep software
// pipeline: next step's 4x dwordx4 gathers are issued before current step's
// math, so the compiler waits with partial vmcnt and keeps >=4 loads in
// flight per wave at all times.
// Path len >= 8 so step 0 is always fully valid. Step 2 covers nodes 16..19
// (groups 0..3); groups 4..7 use a clamped in-row index with code forced to 0
// (no divergence, and the row is already L1-hot from step 0).
// mask == |code| (codes are +/-1 valid, 0 pad) -> masks input unused.
// NO device-scope fences/atomics (R3 post-mortem: 8192 __threadfence()s
// serialize L2 writebacks -> 8x regression). Two-kernel reduce instead.
__global__ __launch_bounds__(256) void hs_loss_kernel(
    const int* __restrict__ center, const int* __restrict__ target,
    const float* __restrict__ in_emb, const float* __restrict__ inner_vec,
    const int* __restrict__ paths, const float* __restrict__ codes,
    float* __restrict__ partials)
{
    const int wave = threadIdx.x >> 6;
    const int lane = threadIdx.x & 63;
    const int g    = lane >> 3;   // group 0..7
    const int gl   = lane & 7;    // lane within group
    const int b = blockIdx.x * WPB + wave;

    const int c = center[b];
    const int t = target[b];

    // h fragment: 16 floats (4x float4) per lane
    const float4* hp = (const float4*)(in_emb + (size_t)c * EMBED) + 4 * gl;
    const float4 h0 = hp[0], h1 = hp[1], h2 = hp[2], h3 = hp[3];

    // (path, code) for this group's 3 nodes: g, g+8, g+16(clamped)
    const int base = t * MAX_PATH + g;
    const int  p0 = paths[base];
    const int  p1 = paths[base + 8];
    const int  off2 = (g < 4) ? 16 : 0;          // keep index in-row
    const int  p2 = paths[base + off2];
    const float c0 = codes[base];
    const float c1 = codes[base + 8];
    const float c2 = (g < 4) ? codes[base + 16] : 0.f;

    // ---- software pipeline: load(0), load(1), math(0), load(2), math(1), math(2)
    const float4* v0 = (const float4*)(inner_vec + (size_t)p0 * EMBED) + 4 * gl;
    float4 a0 = v0[0], a1 = v0[1], a2 = v0[2], a3 = v0[3];
    const float4* v1 = (const float4*)(inner_vec + (size_t)p1 * EMBED) + 4 * gl;
    float4 b0 = v1[0], b1 = v1[1], b2 = v1[2], b3 = v1[3];

    float acc = 0.f;
    // --- step 0 math (a*), step 2 loads issued right after a* is consumed
    {
        float d  = h0.x * a0.x;  d = fmaf(h0.y, a0.y, d);
        d = fmaf(h0.z, a0.z, d); d = fmaf(h0.w, a0.w, d);
        float e  = h1.x * a1.x;  e = fmaf(h1.y, a1.y, e);
        e = fmaf(h1.z, a1.z, e); e = fmaf(h1.w, a1.w, e);
        d = fmaf(h2.x, a2.x, d); d = fmaf(h2.y, a2.y, d);
        d = fmaf(h2.z, a2.z, d); d = fmaf(h2.w, a2.w, d);
        e = fmaf(h3.x, a3.x, e); e = fmaf(h3.y, a3.y, e);
        e = fmaf(h3.z, a3.z, e); e = fmaf(h3.w, a3.w, e);
        d += e;
        d += __shfl_xor(d, 1, 64);
        d += __shfl_xor(d, 2, 64);
        d += __shfl_xor(d, 4, 64);
        const float x  = c0 * d;
        const float ls = fminf(x, 0.f) - __logf(1.f + __expf(-fabsf(x)));
        acc = fmaf(fabsf(c0), ls, acc);
    }
    const float4* v2 = (const float4*)(inner_vec + (size_t)p2 * EMBED) + 4 * gl;
    float4 q0 = v2[0], q1 = v2[1], q2 = v2[2], q3 = v2[3];
    // --- step 1 math (b*)
    {
        float d  = h0.x * b0.x;  d = fmaf(h0.y, b0.y, d);
        d = fmaf(h0.z, b0.z, d); d = fmaf(h0.w, b0.w, d);
        float e  = h1.x * b1.x;  e = fmaf(h1.y, b1.y, e);
        e = fmaf(h1.z, b1.z, e); e = fmaf(h1.w, b1.w, e);
        d = fmaf(h2.x, b2.x, d); d = fmaf(h2.y, b2.y, d);
        d = fmaf(h2.z, b2.z, d); d = fmaf(h2.w, b2.w, d);
        e = fmaf(h3.x, b3.x, e); e = fmaf(h3.y, b3.y, e);
        e = fmaf(h3.z, b3.z, e); e = fmaf(h3.w, b3.w, e);
        d += e;
        d += __shfl_xor(d, 1, 64);
        d += __shfl_xor(d, 2, 64);
        d += __shfl_xor(d, 4, 64);
        const float x  = c1 * d;
        const float ls = fminf(x, 0.f) - __logf(1.f + __expf(-fabsf(x)));
        acc = fmaf(fabsf(c1), ls, acc);
    }
    // --- step 2 math (q*)
    {
        float d  = h0.x * q0.x;  d = fmaf(h0.y, q0.y, d);
        d = fmaf(h0.z, q0.z, d); d = fmaf(h0.w, q0.w, d);
        float e  = h1.x * q1.x;  e = fmaf(h1.y, q1.y, e);
        e = fmaf(h1.z, q1.z, e); e = fmaf(h1.w, q1.w, e);
        d = fmaf(h2.x, q2.x, d); d = fmaf(h2.y, q2.y, d);
        d = fmaf(h2.z, q2.z, d); d = fmaf(h2.w, q2.w, d);
        e = fmaf(h3.x, q3.x, e); e = fmaf(h3.y, q3.y, e);
        e = fmaf(h3.z, q3.z, e); e = fmaf(h3.w, q3.w, e);
        d += e;
        d += __shfl_xor(d, 1, 64);
        d += __shfl_xor(d, 2, 64);
        d += __shfl_xor(d, 4, 64);
        const float x  = c2 * d;
        const float ls = fminf(x, 0.f) - __logf(1.f + __expf(-fabsf(x)));
        acc = fmaf(fabsf(c2), ls, acc);   // c2==0 for groups 4..7 -> masked
    }

    // sum across the 8 groups
    acc += __shfl_xor(acc, 8, 64);
    acc += __shfl_xor(acc, 16, 64);
    acc += __shfl_xor(acc, 32, 64);

    __shared__ float ws[WPB];
    if (lane == 0) ws[wave] = -acc;
    __syncthreads();
    if (threadIdx.x == 0) {
        partials[blockIdx.x] = ws[0] + ws[1] + ws[2] + ws[3];
    }
}

__global__ __launch_bounds__(256) void hs_reduce_kernel(
    const float* __restrict__ partials, float* __restrict__ out)
{
    float s = 0.f;
    for (int i = threadIdx.x; i < NBLOCKS; i += 256) s += partials[i];
    #pragma unroll
    for (int off = 32; off; off >>= 1) s += __shfl_xor(s, off, 64);
    __shared__ float ws[4];
    const int wave = threadIdx.x >> 6;
    const int lane = threadIdx.x & 63;
    if (lane == 0) ws[wave] = s;
    __syncthreads();
    if (threadIdx.x == 0) {
        out[0] = (ws[0] + ws[1] + ws[2] + ws[3]) / (float)BATCH;
    }
}

extern "C" void kernel_launch(void* const* d_in, const int* in_sizes, int n_in,
                              void* d_out, int out_size, void* d_ws, size_t ws_size,
                              hipStream_t stream) {
    const int*   center    = (const int*)d_in[0];
    const int*   target    = (const int*)d_in[1];
    const float* in_emb    = (const float*)d_in[2];
    const float* inner_vec = (const float*)d_in[3];
    const int*   paths     = (const int*)d_in[4];
    const float* codes     = (const float*)d_in[5];
    // d_in[6] (masks) intentionally unused: mask == |code|
    float* out = (float*)d_out;
    float* partials = (float*)d_ws;   // 8192 floats = 32 KB scratch

    hs_loss_kernel<<<NBLOCKS, 256, 0, stream>>>(
        center, target, in_emb, inner_vec, paths, codes, partials);
    hs_reduce_kernel<<<1, 256, 0, stream>>>(partials, out);
}

// Round 5
// 164.158 us; speedup vs baseline: 2.9476x; 1.0836x over previous
//
#include <hip/hip_runtime.h>

#define VOCAB 100000
#define EMBED 128
#define MAX_PATH 20
#define BATCH 32768
#define WPB 4                    // waves per block (block = 256 threads)
#define NBLOCKS (BATCH / WPB)    // 8192

// One 64-lane wave per batch element; wave split into 4 groups of 16 lanes,
// each group handling one path node per step (5 steps cover MAX_PATH=20).
//
// KEY LAYOUT RULE (R4 post-mortem): every vector-memory instruction must be
// CONTIGUOUS within a group. Lane gl loads float4 at byte 16*gl and
// 16*gl+256 -> each dwordx4 instruction covers 256 contiguous bytes per
// group = 8 cache lines per wave-instruction (R4's 64B-strided layout hit
// 32 lines/instr and throttled the TA/L1).
//
// __launch_bounds__(256,4): 128-VGPR budget so the compiler keeps h + all
// 10 gather loads in flight (R2/R4 showed VGPR 24-36 = loads were sunk to
// meet the default occupancy target, serializing the latency chain).
//
// Straight-line code, no early-exit (R3 lesson). Padded nodes gather row 0
// (reference zeroes padded path ids) -> L1-hot. mask == |code| -> masks
// input unused. No device-scope fences (R3: 8192 __threadfence()s = 8x
// regression); plain two-kernel reduce.
__global__ __launch_bounds__(256, 4) void hs_loss_kernel(
    const int* __restrict__ center, const int* __restrict__ target,
    const float* __restrict__ in_emb, const float* __restrict__ inner_vec,
    const int* __restrict__ paths, const float* __restrict__ codes,
    float* __restrict__ partials)
{
    const int wave = threadIdx.x >> 6;
    const int lane = threadIdx.x & 63;
    const int g    = lane >> 4;   // group 0..3
    const int gl   = lane & 15;   // lane within group
    const int b = blockIdx.x * WPB + wave;

    const int c = center[b];
    const int t = target[b];

    // h fragment: floats [4gl..4gl+4) and [64+4gl..64+4gl+4)  (contiguous per instr)
    const float4* hp = (const float4*)(in_emb + (size_t)c * EMBED);
    const float4 h0 = hp[gl];
    const float4 h1 = hp[gl + 16];

    // Group g's 5 (path, code) pairs: nodes g, g+4, ..., g+16 (broadcast loads)
    const int base = t * MAX_PATH + g;
    int   p[5];
    float cd[5];
    #pragma unroll
    for (int j = 0; j < 5; ++j) {
        p[j]  = paths[base + 4 * j];
        cd[j] = codes[base + 4 * j];
    }

    // Phase 1: all 10 gather loads issued back-to-back (in flight together).
    float4 a0[5], a1[5];
    #pragma unroll
    for (int j = 0; j < 5; ++j) {
        const float4* ivp = (const float4*)(inner_vec + (size_t)p[j] * EMBED);
        a0[j] = ivp[gl];
        a1[j] = ivp[gl + 16];
    }

    // Phase 2: math.
    float acc = 0.f;
    #pragma unroll
    for (int j = 0; j < 5; ++j) {
        float d = h0.x * a0[j].x;
        d = fmaf(h0.y, a0[j].y, d);
        d = fmaf(h0.z, a0[j].z, d);
        d = fmaf(h0.w, a0[j].w, d);
        float e = h1.x * a1[j].x;
        e = fmaf(h1.y, a1[j].y, e);
        e = fmaf(h1.z, a1[j].z, e);
        e = fmaf(h1.w, a1[j].w, e);
        d += e;
        d += __shfl_xor(d, 1, 64);
        d += __shfl_xor(d, 2, 64);
        d += __shfl_xor(d, 4, 64);
        d += __shfl_xor(d, 8, 64);
        const float x  = cd[j] * d;
        const float ls = fminf(x, 0.f) - __logf(1.f + __expf(-fabsf(x)));
        acc = fmaf(fabsf(cd[j]), ls, acc);   // |code| == mask (0 on padding)
    }

    // sum across the 4 groups
    acc += __shfl_xor(acc, 16, 64);
    acc += __shfl_xor(acc, 32, 64);

    __shared__ float ws[WPB];
    if (lane == 0) ws[wave] = -acc;
    __syncthreads();
    if (threadIdx.x == 0) {
        partials[blockIdx.x] = ws[0] + ws[1] + ws[2] + ws[3];
    }
}

__global__ __launch_bounds__(256) void hs_reduce_kernel(
    const float* __restrict__ partials, float* __restrict__ out)
{
    float s = 0.f;
    for (int i = threadIdx.x; i < NBLOCKS; i += 256) s += partials[i];
    #pragma unroll
    for (int off = 32; off; off >>= 1) s += __shfl_xor(s, off, 64);
    __shared__ float ws[4];
    const int wave = threadIdx.x >> 6;
    const int lane = threadIdx.x & 63;
    if (lane == 0) ws[wave] = s;
    __syncthreads();
    if (threadIdx.x == 0) {
        out[0] = (ws[0] + ws[1] + ws[2] + ws[3]) / (float)BATCH;
    }
}

extern "C" void kernel_launch(void* const* d_in, const int* in_sizes, int n_in,
                              void* d_out, int out_size, void* d_ws, size_t ws_size,
                              hipStream_t stream) {
    const int*   center    = (const int*)d_in[0];
    const int*   target    = (const int*)d_in[1];
    const float* in_emb    = (const float*)d_in[2];
    const float* inner_vec = (const float*)d_in[3];
    const int*   paths     = (const int*)d_in[4];
    const float* codes     = (const float*)d_in[5];
    // d_in[6] (masks) intentionally unused: mask == |code|
    float* out = (float*)d_out;
    float* partials = (float*)d_ws;   // 8192 floats = 32 KB scratch

    hs_loss_kernel<<<NBLOCKS, 256, 0, stream>>>(
        center, target, in_emb, inner_vec, paths, codes, partials);
    hs_reduce_kernel<<<1, 256, 0, stream>>>(partials, out);
}